// Round 7
// baseline (1486.818 us; speedup 1.0000x reference)
//
#include <hip/hip_runtime.h>

// Batched box-QP via ADMM (rho=1, 50 iters). One 1024-thread block per batch.
// M = Q + I (SPD) inverted in LDS by a rank-8 blocked symmetric sweep on the
// packed quad-padded lower triangle.
//
// R6 design (64-VGPR-budget-safe: 4x8 slabs, per-wave register sweep of the
// 8x8 pivot block, LDS-read matvec) + R7 fix: the pivot-block writeback runs
// in a DIVERGENT branch (1-2 threads), where __shfl reads from exec-inactive
// lanes return zero/undefined on CDNA -> route S through SL[8][9] in LDS
// (divergence-safe), written by fully-active wave 0 after the sweep.

#define NX     256
#define NITER  50
#define NTHR   1024
#define NSLAB  1056
#define PTF    264

#define OFF_PT  33280
#define OFF_WT  (OFF_PT + 8 * PTF)   // 35392
#define OFF_W8  (OFF_WT + 8 * PTF)   // 37504
#define OFF_SL  (OFF_W8 + 2048)      // 39552
#define LDS_F   (OFF_SL + 72)        // 39624 floats = 158496 B

__host__ __device__ constexpr int rowoff(int r) {   // packed row offset (floats)
    return 4 * ((r >> 2) + 1) * (((r >> 2) << 1) + (r & 3));
}
__device__ __forceinline__ int physq(int q) { return q ^ ((q >> 3) & 7); }
__device__ __forceinline__ int physf(int i) { return 4 * physq(i >> 2) + (i & 3); }

// slab s (co-major): co = max k with k*(65-k) <= s ; rq = 2co + (s - co*(65-co))
__device__ __forceinline__ void slab_coords(int s, int& rq, int& co) {
    int c = 0;
    #pragma unroll
    for (int k = 1; k < 32; ++k) c += (k * (65 - k) <= s) ? 1 : 0;
    co = c;
    rq = 2 * c + (s - c * (65 - c));
}

template <int J0>
__device__ __forceinline__ float chunk_dot(const float* tri, const float* vb, int r) {
    float acc = 0.f;
    if (r >= J0 + 63) {                 // chunk fully lower: contiguous quads
        const float4* row4 = (const float4*)(tri + rowoff(r) + J0);
        const float4* v4   = (const float4*)(vb + J0);
        #pragma unroll
        for (int m2 = 0; m2 < 16; ++m2) {
            const float4 a = row4[m2], v = v4[m2];
            acc += a.x * v.x + a.y * v.y + a.z * v.z + a.w * v.w;
        }
    } else if (r < J0) {                // fully upper: compile-time row offsets
        #pragma unroll
        for (int jj = 0; jj < 64; ++jj)
            acc += tri[rowoff(J0 + jj) + r] * vb[J0 + jj];
    } else {                            // mixed (few waves)
        const int ror = rowoff(r);
        #pragma unroll
        for (int jj = 0; jj < 64; ++jj) {
            const int j = J0 + jj;
            const int addr = (j <= r) ? (ror + j) : (rowoff(j) + r);
            acc += tri[addr] * vb[j];
        }
    }
    return acc;
}

__global__ void __launch_bounds__(NTHR, 1)
boxqp_r7_kernel(const float* __restrict__ Q,
                const float* __restrict__ p,
                const float* __restrict__ lb,
                const float* __restrict__ ub,
                float* __restrict__ out)
{
    __shared__ float lds[LDS_F];
    float*  tri  = lds;
    float4* tri4 = (float4*)lds;
    float*  PT   = lds + OFF_PT;   // P transposed [8][PTF], physf-swizzled cols
    float*  WT   = lds + OFF_WT;   // W transposed [8][PTF], linear
    float*  W8   = lds + OFF_W8;   // W row-major [256][8]
    float*  SL   = lds + OFF_SL;   // swept pivot block [8][9] (divergence-safe)
    float*  part = lds + OFF_PT;   // matvec-phase alias (1024 f)
    float*  vbuf = lds + OFF_WT;   // matvec-phase alias (256 f)

    const int t    = threadIdx.x;
    const int lane = t & 63;
    const int b    = blockIdx.x;
    const size_t qbase = ((size_t)b) << 16;

    // --- slab assignments: s0 = t, s1 = 1024 + t (t < 32) ---
    int rq0, co0, rq1, co1;
    slab_coords(t, rq0, co0);
    const bool has2 = (t < (NSLAB - NTHR));
    slab_coords(has2 ? (NTHR + t) : 0, rq1, co1);

    // --- load lower triangle of M = Q + I, slab by slab ---
    auto load_slab = [&](int rq, int co) {
        const int r0 = rq << 2, j0q = co << 1;
        const bool dg  = ((rq >> 1) == co);      // slab touches diagonal
        const bool top = (rq == (co << 1));      // h=1 quad beyond allocation
        #pragma unroll
        for (int s2 = 0; s2 < 4; ++s2) {
            const int r  = r0 + s2;
            const int ro = rowoff(r) >> 2;
            #pragma unroll
            for (int h = 0; h < 2; ++h) {
                if (h == 1 && top) continue;
                const int gq = j0q + h;
                float4 v = *(const float4*)(Q + qbase + ((size_t)r << 8) + (gq << 2));
                if (dg) {
                    const int c0 = gq << 2;
                    v.x = (c0 + 0 > r) ? 0.f : (v.x + (c0 + 0 == r ? 1.f : 0.f));
                    v.y = (c0 + 1 > r) ? 0.f : (v.y + (c0 + 1 == r ? 1.f : 0.f));
                    v.z = (c0 + 2 > r) ? 0.f : (v.z + (c0 + 2 == r ? 1.f : 0.f));
                    v.w = (c0 + 3 > r) ? 0.f : (v.w + (c0 + 3 == r ? 1.f : 0.f));
                }
                tri4[ro + gq] = v;
            }
        }
    };
    load_slab(rq0, co0);
    if (has2) load_slab(rq1, co1);
    __syncthreads();

    // --- per-thread phase constants ---
    const int i1    = t >> 1;                    // phase-1 row (t < 512)
    const int h1    = t & 1;
    const int rowQ1 = rowoff(i1 & 255) >> 2;
    const int pfi   = physf(i1 & 255);
    const int pfT   = physf(t & 255);            // phase-2 (t < 256)

    // --- phase-3 worker (Schur / writebacks); pivot block reads SL ---
    auto update_slab = [&](int rq, int co, int kb) {
        const int r0 = rq << 2, j0q = co << 1;
        const bool top = (rq == (co << 1));
        int roQ[4];
        #pragma unroll
        for (int s2 = 0; s2 < 4; ++s2) roQ[s2] = rowoff(r0 + s2) >> 2;

        if ((rq >> 1) == kb) {
            if (co == kb) {                       // pivot block <- S (from SL)
                #pragma unroll
                for (int s2 = 0; s2 < 4; ++s2) {
                    const int sr = ((rq & 1) << 2) | s2;
                    #pragma unroll
                    for (int h = 0; h < 2; ++h) {
                        if (h == 1 && top) continue;
                        float4 v;
                        v.x = SL[sr * 9 + (h << 2) + 0];
                        v.y = SL[sr * 9 + (h << 2) + 1];
                        v.z = SL[sr * 9 + (h << 2) + 2];
                        v.w = SL[sr * 9 + (h << 2) + 3];
                        tri4[roQ[s2] + j0q + h] = v;
                    }
                }
            } else {                              // pivot rows <- W^T
                #pragma unroll
                for (int s2 = 0; s2 < 4; ++s2) {
                    const int sr = ((rq & 1) << 2) | s2;
                    tri4[roQ[s2] + j0q + 0] = *(const float4*)(WT + sr * PTF + (j0q << 2));
                    tri4[roQ[s2] + j0q + 1] = *(const float4*)(WT + sr * PTF + (j0q << 2) + 4);
                }
            }
        } else if (co == kb) {                    // panel <- W
            #pragma unroll
            for (int s2 = 0; s2 < 4; ++s2) {
                tri4[roQ[s2] + j0q + 0] = *(const float4*)(W8 + ((r0 + s2) << 3));
                tri4[roQ[s2] + j0q + 1] = *(const float4*)(W8 + ((r0 + s2) << 3) + 4);
            }
        } else {                                  // Schur: A -= W * P^T
            const int pq0 = physq(j0q) << 2, pq1 = physq(j0q + 1) << 2;
            float4 a0[4], a1[4];
            #pragma unroll
            for (int s2 = 0; s2 < 4; ++s2) {
                a0[s2] = tri4[roQ[s2] + j0q + 0];
                a1[s2] = tri4[roQ[s2] + j0q + 1];
            }
            #pragma unroll
            for (int m = 0; m < 8; ++m) {
                const float4 pa = *(const float4*)(PT + m * PTF + pq0);
                const float4 pb = *(const float4*)(PT + m * PTF + pq1);
                const float4 wq = *(const float4*)(WT + m * PTF + r0);
                #define UPD(s2, wc) \
                    a0[s2].x -= (wc) * pa.x; a0[s2].y -= (wc) * pa.y; \
                    a0[s2].z -= (wc) * pa.z; a0[s2].w -= (wc) * pa.w; \
                    a1[s2].x -= (wc) * pb.x; a1[s2].y -= (wc) * pb.y; \
                    a1[s2].z -= (wc) * pb.z; a1[s2].w -= (wc) * pb.w;
                UPD(0, wq.x) UPD(1, wq.y) UPD(2, wq.z) UPD(3, wq.w)
                #undef UPD
            }
            #pragma unroll
            for (int s2 = 0; s2 < 4; ++s2) {
                tri4[roQ[s2] + j0q + 0] = a0[s2];
                if (!top) tri4[roQ[s2] + j0q + 1] = a1[s2];
            }
        }
    };

    // --- rank-8 blocked sweep: 32 steps; tri becomes -(M^{-1}) ---
    for (int kb = 0; kb < 32; ++kb) {
        const int k0 = kb << 3;

        // phase 1: snapshot panel P[i][0..7] -> PT (transposed, swizzled)
        if (t < 512) {
            const int i = i1;
            float v0, v1, v2, v3;
            if (i >= k0 + 8) {
                const float4 v = tri4[rowQ1 + (kb << 1) + h1];
                v0 = v.x; v1 = v.y; v2 = v.z; v3 = v.w;
            } else {
                const int roi = rowoff(i);
                const int km  = k0 + (h1 << 2);
                v0 = (km + 0 <= i) ? tri[roi + km + 0] : tri[rowoff(km + 0) + i];
                v1 = (km + 1 <= i) ? tri[roi + km + 1] : tri[rowoff(km + 1) + i];
                v2 = (km + 2 <= i) ? tri[roi + km + 2] : tri[rowoff(km + 2) + i];
                v3 = (km + 3 <= i) ? tri[roi + km + 3] : tri[rowoff(km + 3) + i];
            }
            const int rb = (h1 << 2) * PTF + pfi;
            PT[rb + 0 * PTF] = v0;
            PT[rb + 1 * PTF] = v1;
            PT[rb + 2 * PTF] = v2;
            PT[rb + 3 * PTF] = v3;
        }
        __syncthreads();

        // every wave (all lanes active): sweep the 8x8 pivot block in-register
        float S;
        {
            const int a = lane >> 3, bb = lane & 7;
            S = PT[bb * PTF + physf(k0 + a)];
            #pragma unroll
            for (int kk = 0; kk < 8; ++kk) {
                const float dkk = __shfl(S, kk * 9);
                const float inv = 1.0f / dkk;
                const float cs  = __shfl(S, (lane & 56) | kk);
                const float rs  = __shfl(S, (kk << 3) | bb);
                const float upd = S - cs * rs * inv;
                const bool ad = (a == kk), bd = (bb == kk);
                S = (ad && bd) ? -inv : (ad ? rs * inv : (bd ? cs * inv : upd));
            }
        }
        // wave 0 (fully active) publishes S for divergent consumers
        if (t < 64) SL[(lane >> 3) * 9 + (lane & 7)] = S;

        // phase 2 (t<256, waves 0-3 fully active -> shfl safe):
        // W[i][:] = -(P[i]·S) -> WT (transposed) + W8
        if (t < 256) {
            float pv[8];
            #pragma unroll
            for (int m = 0; m < 8; ++m) pv[m] = PT[m * PTF + pfT];
            float w[8];
            #pragma unroll
            for (int c = 0; c < 8; ++c) {
                float acc = 0.f;
                #pragma unroll
                for (int m = 0; m < 8; ++m) acc += pv[m] * __shfl(S, (m << 3) | c);
                w[c] = -acc;
                WT[c * PTF + t] = -acc;
            }
            *(float4*)(W8 + (t << 3) + 0) = make_float4(w[0], w[1], w[2], w[3]);
            *(float4*)(W8 + (t << 3) + 4) = make_float4(w[4], w[5], w[6], w[7]);
        }
        __syncthreads();   // SL, WT, W8 ready

        // phase 3: per-slab update
        update_slab(rq0, co0, kb);
        if (has2) update_slab(rq1, co1, kb);
        __syncthreads();
    }

    // --- ADMM iterations: x = tri·vbuf (tri = -Minv, vbuf = u+p-z = -rhs) ---
    const int mr = t & 255;   // row handled in dot phase
    const int q4 = t >> 8;    // wave-uniform chunk id

    float x = 0.f, z = 0.f, uu = 0.f;
    float pi = 0.f, lbi = 0.f, ubi = 0.f;
    if (t < 256) {
        const int gb = (b << 8) + t;
        pi = p[gb]; lbi = lb[gb]; ubi = ub[gb];
        vbuf[t] = pi;                       // z=u=0 -> vbuf = p
    }
    __syncthreads();

    for (int it = 0; it < NITER; ++it) {
        float acc;
        switch (q4) {
            case 0:  acc = chunk_dot<0  >(tri, vbuf, mr); break;
            case 1:  acc = chunk_dot<64 >(tri, vbuf, mr); break;
            case 2:  acc = chunk_dot<128>(tri, vbuf, mr); break;
            default: acc = chunk_dot<192>(tri, vbuf, mr); break;
        }
        part[(q4 << 8) | mr] = acc;
        __syncthreads();
        if (t < 256) {
            x = part[t] + part[256 + t] + part[512 + t] + part[768 + t];
            const float xu = x + uu;
            z  = fminf(fmaxf(xu, lbi), ubi);
            uu = xu - z;
            vbuf[t] = (uu + pi) - z;
        }
        __syncthreads();
    }

    if (t < 256) out[(b << 8) + t] = x;
}

extern "C" void kernel_launch(void* const* d_in, const int* in_sizes, int n_in,
                              void* d_out, int out_size, void* d_ws, size_t ws_size,
                              hipStream_t stream) {
    const float* Q  = (const float*)d_in[0];
    const float* p  = (const float*)d_in[1];
    const float* lb = (const float*)d_in[2];
    const float* ub = (const float*)d_in[3];
    float* out = (float*)d_out;

    hipLaunchKernelGGL(boxqp_r7_kernel, dim3(256), dim3(NTHR), 0, stream,
                       Q, p, lb, ub, out);
}